// Round 4
// baseline (456.734 us; speedup 1.0000x reference)
//
#include <hip/hip_runtime.h>

#define Bv 32
#define Tv 2048
#define Hv 512
#define Dv 1024

using bf16x8 = __attribute__((ext_vector_type(8))) __bf16;
using bf16x4 = __attribute__((ext_vector_type(4))) __bf16;
using f32x4  = __attribute__((ext_vector_type(4))) float;

// ---------------------------------------------------------------------------
// Prep kernel (fused): blocks 0..255 swizzle We -> bf16 B-fragment order;
// blocks 256..767 compute hp[b][h] = hidden[b,:].Wh[h,:] + b_attn[h].
// ---------------------------------------------------------------------------
__global__ void prep_kernel(const float* __restrict__ W, bf16x8* __restrict__ We_sw,
                            const float* __restrict__ hidden,
                            const float* __restrict__ b_attn, float* __restrict__ hp) {
    if (blockIdx.x < 256) {
        int g = blockIdx.x * 256 + threadIdx.x;   // 0..65535
        int h = g >> 7;                           // 512 rows
        int d = (g & 127) * 8;                    // 8 consecutive d's
        const float* src = W + h * (2 * Dv) + Dv + d;
        float4 f0 = *(const float4*)src;
        float4 f1 = *(const float4*)(src + 4);
        bf16x8 o;
        o[0] = (__bf16)f0.x; o[1] = (__bf16)f0.y; o[2] = (__bf16)f0.z; o[3] = (__bf16)f0.w;
        o[4] = (__bf16)f1.x; o[5] = (__bf16)f1.y; o[6] = (__bf16)f1.z; o[7] = (__bf16)f1.w;
        int s = ((h >> 4) * 32 + (d >> 5)) * 64 + (((d >> 3) & 3) << 4) + (h & 15);
        We_sw[s] = o;
    } else {
        int h   = blockIdx.x - 256;
        int tid = threadIdx.x;           // 256
        float4 wh = ((const float4*)(W + h * (2 * Dv)))[tid];
        __shared__ float red[4][Bv];
        int lane = tid & 63, w = tid >> 6;
        for (int b = 0; b < Bv; ++b) {
            float4 x = ((const float4*)(hidden + b * Dv))[tid];
            float p = wh.x * x.x + wh.y * x.y + wh.z * x.z + wh.w * x.w;
#pragma unroll
            for (int m = 1; m < 64; m <<= 1) p += __shfl_xor(p, m);
            if (lane == 0) red[w][b] = p;
        }
        __syncthreads();
        if (tid < Bv)
            hp[tid * Hv + h] = red[0][tid] + red[1][tid] + red[2][tid] + red[3][tid] + b_attn[h];
    }
}

__device__ __forceinline__ float fast_tanh(float x) {
    float xc = fminf(fmaxf(x, -9.0f), 9.0f);
    float e  = __expf(2.0f * xc);
    return 1.0f - 2.0f / (e + 1.0f);
}

// ---------------------------------------------------------------------------
// Main kernel: scores[b,t] = sum_h v[h]*tanh( enc[b,t,:].We[h,:] + hp[b,h] )
// Block = 64 rows x 512 h, 8 waves, wave w owns h in [64w, 64w+64).
// - LDS A-tile: r2's 72-stride row-major layout (measured 0 bank conflicts),
//   double-buffered, ONE lgkm-only barrier per chunk (vmcnt NOT drained).
// - A global loads depth-2 pipelined (fa/fb).
// - B fragments loaded per-ktl directly from L2 (no prefetch regs) — latency
//   hidden by wave TLP once 2 blocks/CU are resident.
// - __launch_bounds__(512,4): forces total regs <= 128 -> 2 blocks/CU.
// ---------------------------------------------------------------------------
__global__ __launch_bounds__(512, 4) void attn_main(
    const float* __restrict__ enc, const bf16x8* __restrict__ Bg,
    const float* __restrict__ hp, const float* __restrict__ vvec,
    float* __restrict__ scores)
{
    __shared__ __align__(16) __bf16 Abuf[2][64 * 72];  // 2 x 9216 B
    __shared__ float redbuf[8][64];

    const int tid   = threadIdx.x;
    const int lane  = tid & 63;
    const int w     = tid >> 6;          // wave 0..7
    const int row0  = blockIdx.x * 64;
    const int batch = row0 >> 11;

    // --- A staging map (coalesced): row = tid>>3, segments (tid&7)*4 and +32
    const int srow = tid >> 3;           // 0..63
    const int sd0  = (tid & 7) * 4;      // 0..28
    const float* gA = enc + (row0 + srow) * Dv + sd0;
    __bf16* lw0 = &Abuf[0][srow * 72 + sd0];

    // --- B fragment base: frag(j,ktl,kc) at Bg[((w*4+j)*32 + kc*2+ktl)*64 + lane]
    const bf16x8* Bptr = Bg + (w * 128) * 64 + lane;

    f32x4 acc[4][4];
#pragma unroll
    for (int i = 0; i < 4; ++i)
#pragma unroll
        for (int j = 0; j < 4; ++j)
            acc[i][j] = (f32x4){0.f, 0.f, 0.f, 0.f};

    // prologue: A chunks 0,1 in flight
    float4 fa0 = *(const float4*)gA;
    float4 fa1 = *(const float4*)(gA + 32);
    float4 fb0 = *(const float4*)(gA + 64);
    float4 fb1 = *(const float4*)(gA + 96);

    const int arow  = lane & 15;
    const int acol8 = (lane >> 4) * 8;

#pragma unroll
    for (int kc = 0; kc < 16; ++kc) {
        // convert + store A(kc) into buf kc&1 (fa issued 2 chunks ago)
        __bf16* p = lw0 + (kc & 1) * (64 * 72);
        bf16x4 o0, o1;
        o0[0] = (__bf16)fa0.x; o0[1] = (__bf16)fa0.y; o0[2] = (__bf16)fa0.z; o0[3] = (__bf16)fa0.w;
        o1[0] = (__bf16)fa1.x; o1[1] = (__bf16)fa1.y; o1[2] = (__bf16)fa1.z; o1[3] = (__bf16)fa1.w;
        *(bf16x4*)p        = o0;
        *(bf16x4*)(p + 32) = o1;

        // LDS-visibility-only barrier: vmcnt NOT drained, prefetches stay live
        asm volatile("s_waitcnt lgkmcnt(0)\n\ts_barrier" ::: "memory");

        // rotate A pipeline; issue A(kc+2)
        fa0 = fb0; fa1 = fb1;
        if (kc < 14) {
            fb0 = *(const float4*)(gA + (kc + 2) * 64);
            fb1 = *(const float4*)(gA + (kc + 2) * 64 + 32);
        }

        const __bf16* rb = &Abuf[kc & 1][0];
#pragma unroll
        for (int ktl = 0; ktl < 2; ++ktl) {
            // B fragments for this ktl-step: 4 loads from L2, issued before the
            // LDS fragment reads so the two latencies overlap
            bf16x8 b0 = Bptr[(0 * 32 + kc * 2 + ktl) * 64];
            bf16x8 b1 = Bptr[(1 * 32 + kc * 2 + ktl) * 64];
            bf16x8 b2 = Bptr[(2 * 32 + kc * 2 + ktl) * 64];
            bf16x8 b3 = Bptr[(3 * 32 + kc * 2 + ktl) * 64];
            bf16x8 a0 = *(const bf16x8*)(rb + (0 * 16 + arow) * 72 + ktl * 32 + acol8);
            bf16x8 a1 = *(const bf16x8*)(rb + (1 * 16 + arow) * 72 + ktl * 32 + acol8);
            bf16x8 a2 = *(const bf16x8*)(rb + (2 * 16 + arow) * 72 + ktl * 32 + acol8);
            bf16x8 a3 = *(const bf16x8*)(rb + (3 * 16 + arow) * 72 + ktl * 32 + acol8);
            acc[0][0] = __builtin_amdgcn_mfma_f32_16x16x32_bf16(a0, b0, acc[0][0], 0, 0, 0);
            acc[1][0] = __builtin_amdgcn_mfma_f32_16x16x32_bf16(a1, b0, acc[1][0], 0, 0, 0);
            acc[2][0] = __builtin_amdgcn_mfma_f32_16x16x32_bf16(a2, b0, acc[2][0], 0, 0, 0);
            acc[3][0] = __builtin_amdgcn_mfma_f32_16x16x32_bf16(a3, b0, acc[3][0], 0, 0, 0);
            acc[0][1] = __builtin_amdgcn_mfma_f32_16x16x32_bf16(a0, b1, acc[0][1], 0, 0, 0);
            acc[1][1] = __builtin_amdgcn_mfma_f32_16x16x32_bf16(a1, b1, acc[1][1], 0, 0, 0);
            acc[2][1] = __builtin_amdgcn_mfma_f32_16x16x32_bf16(a2, b1, acc[2][1], 0, 0, 0);
            acc[3][1] = __builtin_amdgcn_mfma_f32_16x16x32_bf16(a3, b1, acc[3][1], 0, 0, 0);
            acc[0][2] = __builtin_amdgcn_mfma_f32_16x16x32_bf16(a0, b2, acc[0][2], 0, 0, 0);
            acc[1][2] = __builtin_amdgcn_mfma_f32_16x16x32_bf16(a1, b2, acc[1][2], 0, 0, 0);
            acc[2][2] = __builtin_amdgcn_mfma_f32_16x16x32_bf16(a2, b2, acc[2][2], 0, 0, 0);
            acc[3][2] = __builtin_amdgcn_mfma_f32_16x16x32_bf16(a3, b2, acc[3][2], 0, 0, 0);
            acc[0][3] = __builtin_amdgcn_mfma_f32_16x16x32_bf16(a0, b3, acc[0][3], 0, 0, 0);
            acc[1][3] = __builtin_amdgcn_mfma_f32_16x16x32_bf16(a1, b3, acc[1][3], 0, 0, 0);
            acc[2][3] = __builtin_amdgcn_mfma_f32_16x16x32_bf16(a2, b3, acc[2][3], 0, 0, 0);
            acc[3][3] = __builtin_amdgcn_mfma_f32_16x16x32_bf16(a3, b3, acc[3][3], 0, 0, 0);
        }
    }

    // Epilogue. C/D layout: col = lane&15, row = (lane>>4)*4 + reg
    float hpv[4], vv[4];
#pragma unroll
    for (int j = 0; j < 4; ++j) {
        int n  = w * 64 + j * 16 + (lane & 15);
        hpv[j] = hp[batch * Hv + n];
        vv[j]  = vvec[n];
    }
    const int qrow = (lane >> 4) * 4;
#pragma unroll
    for (int mt = 0; mt < 4; ++mt)
#pragma unroll
        for (int r = 0; r < 4; ++r) {
            float p = 0.f;
#pragma unroll
            for (int j = 0; j < 4; ++j)
                p += vv[j] * fast_tanh(acc[mt][j][r] + hpv[j]);
            p += __shfl_xor(p, 1);
            p += __shfl_xor(p, 2);
            p += __shfl_xor(p, 4);
            p += __shfl_xor(p, 8);
            if ((lane & 15) == 0)
                redbuf[w][mt * 16 + qrow + r] = p;
        }
    __syncthreads();
    if (tid < 64) {
        float s = 0.f;
#pragma unroll
        for (int ww = 0; ww < 8; ++ww) s += redbuf[ww][tid];
        scores[row0 + tid] = s;
    }
}

// ---------------------------------------------------------------------------
// Softmax over T per batch row (fp32)
// ---------------------------------------------------------------------------
__global__ void softmax_kernel(const float* __restrict__ scores, float* __restrict__ out) {
    int b   = blockIdx.x;
    int tid = threadIdx.x;               // 256
    const float* s = scores + b * Tv;
    float local[8];
    float m = -1e30f;
#pragma unroll
    for (int i = 0; i < 8; ++i) { local[i] = s[tid + i * 256]; m = fmaxf(m, local[i]); }
    __shared__ float red[4];
    int lane = tid & 63, w = tid >> 6;
#pragma unroll
    for (int x = 1; x < 64; x <<= 1) m = fmaxf(m, __shfl_xor(m, x));
    if (lane == 0) red[w] = m;
    __syncthreads();
    m = fmaxf(fmaxf(red[0], red[1]), fmaxf(red[2], red[3]));
    float sum = 0.f;
#pragma unroll
    for (int i = 0; i < 8; ++i) { local[i] = expf(local[i] - m); sum += local[i]; }
#pragma unroll
    for (int x = 1; x < 64; x <<= 1) sum += __shfl_xor(sum, x);
    __syncthreads();
    if (lane == 0) red[w] = sum;
    __syncthreads();
    sum = red[0] + red[1] + red[2] + red[3];
    float inv = 1.0f / sum;
#pragma unroll
    for (int i = 0; i < 8; ++i) out[b * Tv + tid + i * 256] = local[i] * inv;
}

// ---------------------------------------------------------------------------
extern "C" void kernel_launch(void* const* d_in, const int* in_sizes, int n_in,
                              void* d_out, int out_size, void* d_ws, size_t ws_size,
                              hipStream_t stream) {
    const float* hidden = (const float*)d_in[0];   // (32, 1024)
    const float* enc    = (const float*)d_in[1];   // (32, 2048, 1024)
    const float* W      = (const float*)d_in[2];   // (512, 2048)
    const float* b_attn = (const float*)d_in[3];   // (512,)
    const float* v      = (const float*)d_in[4];   // (512,)
    float* out = (float*)d_out;                    // (32, 1, 2048) fp32

    char* ws = (char*)d_ws;
    bf16x8* We_sw = (bf16x8*)ws;                          // 1 MB
    float*  hp    = (float*)(ws + (1 << 20));             // 64 KB
    float*  sc    = (float*)(ws + (1 << 20) + (1 << 16)); // 256 KB

    prep_kernel<<<768, 256, 0, stream>>>(W, We_sw, hidden, b_attn, hp);
    attn_main<<<(Bv * Tv) / 64, 512, 0, stream>>>(enc, We_sw, hp, v, sc);
    softmax_kernel<<<Bv, 256, 0, stream>>>(sc, out);
}